// Round 12
// baseline (154.475 us; speedup 1.0000x reference)
//
#include <hip/hip_runtime.h>

#define TPB 256

using half8  = __attribute__((ext_vector_type(8))) _Float16;
using fp16x2 = __attribute__((ext_vector_type(2))) __fp16;
using hv2    = __attribute__((ext_vector_type(2))) _Float16;
using f32x4  = __attribute__((ext_vector_type(4))) float;

static __device__ __forceinline__ unsigned pkrtz(float a, float b) {
    fp16x2 h = __builtin_amdgcn_cvt_pkrtz(a, b);
    return __builtin_bit_cast(unsigned, h);
}
static __device__ __forceinline__ hv2 pk2(float a, float b) {
    fp16x2 h = __builtin_amdgcn_cvt_pkrtz(a, b);
    return __builtin_bit_cast(hv2, h);
}
template <int CTRL>
static __device__ __forceinline__ float dppmov(float x) {
    return __int_as_float(__builtin_amdgcn_mov_dpp(__float_as_int(x), CTRL, 0xF, 0xF, true));
}

// ---------- kernel 1: per-JOB shared L1 via 4-way split matvec (f16 s-table) + scan; last block: weight frags ----------
// W2 fragment uses column permutation sigma(nt,m) = 8*(m>>2) + (m&3) + 4*(nt&1) + 32*(nt>>1) so that the
// swapped-operand L2 MFMA (D = W2^T * h1^T) leaves lane (n,q) holding exactly h2[n][8q..8q+7 | 32+8q..+7],
// i.e. the ready-made L3 A-fragment — no LDS transpose needed in k_mlp.
__global__ __launch_bounds__(TPB) void k_prep(const float* __restrict__ x,
                                              const float* __restrict__ h_dag,
                                              const float* __restrict__ h_glob,
                                              const int* __restrict__ ptr,
                                              const int* __restrict__ job_indices,
                                              const int* __restrict__ num_exec_acts,
                                              int J, int nb,
                                              unsigned* __restrict__ s16,
                                              int* __restrict__ bsum, int* __restrict__ jsv,
                                              const float* __restrict__ W1,
                                              const float* __restrict__ b1,
                                              const float* __restrict__ W2,
                                              const float* __restrict__ b2,
                                              const float* __restrict__ W3,
                                              const float* __restrict__ b3,
                                              const float* __restrict__ W4,
                                              uint4* __restrict__ wfrag,
                                              float4* __restrict__ bfrag)
{
    if (blockIdx.x == (unsigned)(4 * nb)) {
        if (threadIdx.x < 64) {
            int lane = threadIdx.x;
            int n = lane & 15, q = lane >> 4;
#pragma unroll
            for (int nt = 0; nt < 4; nt++) {
                const int sig = 8 * (n >> 2) + (n & 3) + 4 * (nt & 1) + 32 * (nt >> 1);
#pragma unroll
                for (int s = 0; s < 2; s++) {
                    half8 w2f;
#pragma unroll
                    for (int jj = 0; jj < 8; jj++) {
                        int ks = s * 32 + q * 8 + jj;
                        w2f[jj] = (_Float16)W2[ks * 64 + sig];
                    }
                    wfrag[(8 + nt * 2 + s) * 64 + lane] = __builtin_bit_cast(uint4, w2f);
                }
            }
#pragma unroll
            for (int nt = 0; nt < 2; nt++) {
#pragma unroll
                for (int s = 0; s < 2; s++) {
                    half8 w3f;
#pragma unroll
                    for (int jj = 0; jj < 8; jj++) {
                        int ks = s * 32 + q * 8 + jj;
                        w3f[jj] = (_Float16)W3[ks * 32 + nt * 16 + n];
                    }
                    wfrag[(16 + nt * 2 + s) * 64 + lane] = __builtin_bit_cast(uint4, w3f);
                }
            }
            bfrag[2 * 64 + lane] = make_float4(b3[n], b3[16 + n], W4[n], W4[16 + n]);
        }
        return;
    }

    const int qtr = blockIdx.x / nb;        // 0..3
    const int cb  = blockIdx.x - qtr * nb;  // job block
    int j = cb * TPB + threadIdx.x;
    int v = 0;
    if (j < J) {
        int ji   = job_indices[j];
        if (qtr == 0) v = num_exec_acts[ji];
        int node = ptr[ji];
        float f[35];
        f[0] = x[node * 5 + 0];
        f[1] = x[node * 5 + 1];
        f[2] = x[node * 5 + 2];
        float4 hd[4], hg[4];
#pragma unroll
        for (int c4 = 0; c4 < 4; c4++) hd[c4] = *(const float4*)(h_dag + (size_t)ji * 16 + 4 * c4);
#pragma unroll
        for (int c4 = 0; c4 < 4; c4++) hg[c4] = *(const float4*)(h_glob + (size_t)j * 16 + 4 * c4);
#pragma unroll
        for (int c4 = 0; c4 < 4; c4++) {
            f[3 + 4 * c4 + 0]  = hd[c4].x; f[3 + 4 * c4 + 1]  = hd[c4].y;
            f[3 + 4 * c4 + 2]  = hd[c4].z; f[3 + 4 * c4 + 3]  = hd[c4].w;
            f[19 + 4 * c4 + 0] = hg[c4].x; f[19 + 4 * c4 + 1] = hg[c4].y;
            f[19 + 4 * c4 + 2] = hg[c4].z; f[19 + 4 * c4 + 3] = hg[c4].w;
        }
        float acc[16];
#pragma unroll
        for (int d4 = 0; d4 < 4; d4++) {
            float4 b = *(const float4*)(b1 + qtr * 16 + 4 * d4);
            acc[4 * d4 + 0] = b.x; acc[4 * d4 + 1] = b.y;
            acc[4 * d4 + 2] = b.z; acc[4 * d4 + 3] = b.w;
        }
#pragma unroll
        for (int c = 0; c < 35; c++) {
            float fc = f[c];
#pragma unroll
            for (int d4 = 0; d4 < 4; d4++) {
                float4 w = *(const float4*)(W1 + c * 64 + qtr * 16 + 4 * d4);
                acc[4 * d4 + 0] += fc * w.x; acc[4 * d4 + 1] += fc * w.y;
                acc[4 * d4 + 2] += fc * w.z; acc[4 * d4 + 3] += fc * w.w;
            }
        }
        unsigned* dst = s16 + ((size_t)qtr * J + j) * 8;
        ((uint4*)dst)[0] = make_uint4(pkrtz(acc[0], acc[1]),  pkrtz(acc[2], acc[3]),
                                      pkrtz(acc[4], acc[5]),  pkrtz(acc[6], acc[7]));
        ((uint4*)dst)[1] = make_uint4(pkrtz(acc[8], acc[9]),  pkrtz(acc[10], acc[11]),
                                      pkrtz(acc[12], acc[13]), pkrtz(acc[14], acc[15]));
    }
    if (qtr != 0) return;

    __shared__ int sc[TPB];
    sc[threadIdx.x] = v;
    __syncthreads();
    for (int d = 1; d < TPB; d <<= 1) {
        int add = (threadIdx.x >= d) ? sc[threadIdx.x - d] : 0;
        __syncthreads();
        sc[threadIdx.x] += add;
        __syncthreads();
    }
    if (j < J) jsv[j] = ((sc[threadIdx.x] - v) << 6) | v;
    if (threadIdx.x == TPB - 1) bsum[cb] = sc[TPB - 1];
}

// ---------- kernel 2: MLP from f16 s-table; register-only dataflow (swapped-L2, no LDS transpose) ----------
__global__ __launch_bounds__(TPB) void k_mlp_mfma(const unsigned* __restrict__ s16,
                                                  const float* __restrict__ W1,
                                                  const float* __restrict__ b2,
                                                  const int* __restrict__ jsv,
                                                  const int* __restrict__ bsum,
                                                  const uint4* __restrict__ wfrag,
                                                  const float4* __restrict__ bfrag,
                                                  const float* __restrict__ b4,
                                                  float* __restrict__ out,
                                                  int T, int J, int nb, int numTiles, int chunk)
{
    __shared__ int boffs[TPB];                       // exclusive scan of bsum
    __shared__ int swin[4][64];                      // per-wave job-start window
    __shared__ int srow[4][64];                      // per-wave per-row (abs_job<<8|exec) for 64 rows
    const int tid  = threadIdx.x;
    const int lane = tid & 63;
    const int wv   = tid >> 6;
    const int n    = lane & 15;
    const int q    = lane >> 4;

    // ---- block-local exclusive scan of bsum (nb <= 256) ----
    {
        int v = (tid < nb) ? bsum[tid] : 0;
        boffs[tid] = v;
        __syncthreads();
        for (int d = 1; d < TPB; d <<= 1) {
            int add = (tid >= d) ? boffs[tid - d] : 0;
            __syncthreads();
            boffs[tid] += add;
            __syncthreads();
        }
        int ex = boffs[tid] - v;
        __syncthreads();
        boffs[tid] = ex;
        __syncthreads();
    }

    // ---- fragment loads: L2/L3 weights + biases ----
    half8 bw2[4][2], bw3[2][2];
#pragma unroll
    for (int nt = 0; nt < 4; nt++)
#pragma unroll
        for (int s = 0; s < 2; s++)
            bw2[nt][s] = __builtin_bit_cast(half8, wfrag[(8 + nt * 2 + s) * 64 + lane]);
#pragma unroll
    for (int nt = 0; nt < 2; nt++)
#pragma unroll
        for (int s = 0; s < 2; s++)
            bw3[nt][s] = __builtin_bit_cast(half8, wfrag[(16 + nt * 2 + s) * 64 + lane]);

    // swapped-L2 bias: acc2[nt][r] = b2[sigma(nt,4q+r)] = b2[8q + 4*(nt&1) + 32*(nt>>1) + r]
    float4 bb2q[4];
#pragma unroll
    for (int nt = 0; nt < 4; nt++)
        bb2q[nt] = *(const float4*)(b2 + 8 * q + 4 * (nt & 1) + 32 * (nt >> 1));

    float4 bf3 = bfrag[2 * 64 + lane];
    float bb3[2] = {bf3.x, bf3.y};
    const float w4a = bf3.z, w4b = bf3.w;
    const float b4v = b4[0];

    // ---- per-lane w36 slice as f16 pairs ----
    hv2 w36p[8];
    {
        const float* wp = W1 + 35 * 64 + q * 8;
#pragma unroll
        for (int k = 0; k < 4; k++) w36p[k]     = pk2(wp[2 * k],      wp[2 * k + 1]);
#pragma unroll
        for (int k = 0; k < 4; k++) w36p[4 + k] = pk2(wp[32 + 2 * k], wp[32 + 2 * k + 1]);
    }
    const hv2 z2 = {(_Float16)0.0f, (_Float16)0.0f};

    // ---- lane-constant s16 base pointers ----
    const uint4* sbLo = (const uint4*)s16 + ((size_t)(q >> 1) * J) * 2 + (q & 1);
    const uint4* sbHi = (const uint4*)s16 + ((size_t)(2 + (q >> 1)) * J) * 2 + (q & 1);

    // ---- per-block contiguous tile range; wave wv owns the wv-th quarter ----
    const int t0 = blockIdx.x * chunk;
    const int t1 = (t0 + chunk < numTiles) ? (t0 + chunk) : numTiles;
    const int R  = (t1 - t0) * 32;
    const int r0 = t0 * 128 + wv * R;
    int rend = r0 + R;
    if (rend > T) rend = T;

    if (r0 < rend) {
        int j_lo;
        {
            int lo = 0, hi = nb - 1;
            while (lo < hi) {
                int mid = (lo + hi + 1) >> 1;
                if (boffs[mid] <= r0) lo = mid; else hi = mid - 1;
            }
            j_lo = lo << 8;
        }
        int sreg    = 0;
        int win_top = 0x80000000;

        half8 a2[2][2];   // h1 A-frags (== B-frags of h1^T) for one 32-row half

        // ---- h1 build via packed f16: rows 16*(mtbase+m)+n, m=0,1 ----
        auto build_a2 = [&](int mtbase) {
#pragma unroll
            for (int m = 0; m < 2; m++) {
                int u   = srow[wv][16 * (mtbase + m) + n];
                int job = u >> 8;                         // absolute job id
                float e = (float)(u & 255) * 0.02f;
                uint4 lo = sbLo[(size_t)job * 2];
                uint4 hi = sbHi[(size_t)job * 2];
                hv2 epk = pk2(e, e);
                hv2 r0_ = __builtin_elementwise_max(__builtin_bit_cast(hv2, lo.x) + epk * w36p[0], z2);
                hv2 r1_ = __builtin_elementwise_max(__builtin_bit_cast(hv2, lo.y) + epk * w36p[1], z2);
                hv2 r2_ = __builtin_elementwise_max(__builtin_bit_cast(hv2, lo.z) + epk * w36p[2], z2);
                hv2 r3_ = __builtin_elementwise_max(__builtin_bit_cast(hv2, lo.w) + epk * w36p[3], z2);
                a2[m][0] = __builtin_bit_cast(half8, make_uint4(__builtin_bit_cast(unsigned, r0_),
                                                                __builtin_bit_cast(unsigned, r1_),
                                                                __builtin_bit_cast(unsigned, r2_),
                                                                __builtin_bit_cast(unsigned, r3_)));
                hv2 r4_ = __builtin_elementwise_max(__builtin_bit_cast(hv2, hi.x) + epk * w36p[4], z2);
                hv2 r5_ = __builtin_elementwise_max(__builtin_bit_cast(hv2, hi.y) + epk * w36p[5], z2);
                hv2 r6_ = __builtin_elementwise_max(__builtin_bit_cast(hv2, hi.z) + epk * w36p[6], z2);
                hv2 r7_ = __builtin_elementwise_max(__builtin_bit_cast(hv2, hi.w) + epk * w36p[7], z2);
                a2[m][1] = __builtin_bit_cast(half8, make_uint4(__builtin_bit_cast(unsigned, r4_),
                                                                __builtin_bit_cast(unsigned, r5_),
                                                                __builtin_bit_cast(unsigned, r6_),
                                                                __builtin_bit_cast(unsigned, r7_)));
            }
        };

        // ---- full register pipeline for one 16-row m-tile: swapped L2 -> relu/pack -> L3 -> L4 reduce ----
        auto process_mt = [&](int mt, int rbb) {
            // L2 swapped: D = W2sigma^T * h1^T ; lane(n,q) gets h2[batch n][dims 8q+4(nt&1)+r+32(nt>>1)]
            f32x4 acc2[4];
#pragma unroll
            for (int nt = 0; nt < 4; nt++) {
                f32x4 c; c[0] = bb2q[nt].x; c[1] = bb2q[nt].y; c[2] = bb2q[nt].z; c[3] = bb2q[nt].w;
                acc2[nt] = c;
            }
#pragma unroll
            for (int s = 0; s < 2; s++)
#pragma unroll
                for (int nt = 0; nt < 4; nt++)
                    acc2[nt] = __builtin_amdgcn_mfma_f32_16x16x32_f16(bw2[nt][s], a2[mt][s], acc2[nt], 0, 0, 0);

            // ReLU + pack: acc2 IS the L3 A-fragment modulo f16 conversion
            half8 a3[2];
#pragma unroll
            for (int s = 0; s < 2; s++) {
                unsigned u0 = pkrtz(fmaxf(acc2[2 * s][0], 0.0f),     fmaxf(acc2[2 * s][1], 0.0f));
                unsigned u1 = pkrtz(fmaxf(acc2[2 * s][2], 0.0f),     fmaxf(acc2[2 * s][3], 0.0f));
                unsigned u2 = pkrtz(fmaxf(acc2[2 * s + 1][0], 0.0f), fmaxf(acc2[2 * s + 1][1], 0.0f));
                unsigned u3 = pkrtz(fmaxf(acc2[2 * s + 1][2], 0.0f), fmaxf(acc2[2 * s + 1][3], 0.0f));
                a3[s] = __builtin_bit_cast(half8, make_uint4(u0, u1, u2, u3));
            }

            // L3 standard: D = h2 * W3 ; row = batch 4q+r, col = out-dim nt2*16+n
            f32x4 acc3[2];
#pragma unroll
            for (int nt2 = 0; nt2 < 2; nt2++) { f32x4 c; c[0]=c[1]=c[2]=c[3]=bb3[nt2]; acc3[nt2]=c; }
#pragma unroll
            for (int s = 0; s < 2; s++)
#pragma unroll
                for (int nt2 = 0; nt2 < 2; nt2++)
                    acc3[nt2] = __builtin_amdgcn_mfma_f32_16x16x32_f16(a3[s], bw3[nt2][s], acc3[nt2], 0, 0, 0);

            // L4: relu + weighted sum over 32 dims = per-lane pair + 16-lane row reduction
            f32x4 red;
#pragma unroll
            for (int r = 0; r < 4; r++)
                red[r] = fmaxf(acc3[0][r], 0.0f) * w4a + fmaxf(acc3[1][r], 0.0f) * w4b;
#pragma unroll
            for (int r = 0; r < 4; r++) {
                red[r] += dppmov<0x121>(red[r]);   // row_ror:1
                red[r] += dppmov<0x122>(red[r]);   // row_ror:2
                red[r] += dppmov<0x124>(red[r]);   // row_ror:4
                red[r] += dppmov<0x128>(red[r]);   // row_ror:8
            }
            int t = rbb + 16 * mt + q * 4 + n;
            float val = (n == 0) ? red[0] : (n == 1) ? red[1] : (n == 2) ? red[2] : red[3];
            if (n < 4 && t < T) out[t] = val + b4v;
        };

        for (int rb = r0; rb < rend; rb += 64) {
            // ---- refill job-start window when it may not cover [rb, rb+64) ----
            if (win_top <= rb + 63) {
                for (;;) {
                    int jj = j_lo + lane;
                    sreg = (jj < J) ? (boffs[jj >> 8] + (jsv[jj] >> 6)) : 0x7fffffff;
                    unsigned long long m = __ballot(sreg <= rb);
                    int adv = 63 - __builtin_clzll(m);
                    j_lo += adv;
                    if (adv == 0) break;
                }
                swin[wv][lane] = sreg;
                win_top = __shfl(sreg, 63);
            }

            // ---- full-wave per-row search: lane resolves row rb+lane; store ABSOLUTE job ----
            {
                int rt = rb + lane;
                const int* sw = swin[wv];
                int lj = 0;
#pragma unroll
                for (int stp = 32; stp; stp >>= 1) {
                    int c2 = lj + stp;
                    if (c2 < 64 && sw[c2] <= rt) lj = c2;
                }
                int job = j_lo + lj;
                if (job > J - 1) job = J - 1;
                srow[wv][lane] = (job << 8) | (rt - sw[lj]);
            }
            // same-wave LDS: DS pipe is in-order, no barrier needed

            build_a2(0);
            process_mt(0, rb);
            process_mt(1, rb);
            if (rb + 32 < rend) {
                build_a2(2);
                process_mt(0, rb + 32);
                process_mt(1, rb + 32);
            }
        }
    }
}

extern "C" void kernel_launch(void* const* d_in, const int* in_sizes, int n_in,
                              void* d_out, int out_size, void* d_ws, size_t ws_size,
                              hipStream_t stream)
{
    const float* x             = (const float*)d_in[0];
    const float* h_dag         = (const float*)d_in[1];
    const float* h_glob        = (const float*)d_in[2];
    const int*   ptr           = (const int*)d_in[3];
    const int*   job_indices   = (const int*)d_in[4];
    const int*   num_exec_acts = (const int*)d_in[5];
    const float* W1 = (const float*)d_in[7];
    const float* b1 = (const float*)d_in[8];
    const float* W2 = (const float*)d_in[9];
    const float* b2 = (const float*)d_in[10];
    const float* W3 = (const float*)d_in[11];
    const float* b3 = (const float*)d_in[12];
    const float* W4 = (const float*)d_in[13];
    const float* b4 = (const float*)d_in[14];
    float* out = (float*)d_out;

    int J  = in_sizes[4];
    int T  = in_sizes[6];
    int nb = (J + TPB - 1) / TPB;

    // workspace layout
    char* wsp = (char*)d_ws;
    int* bsum = (int*)wsp;
    wsp += (((size_t)nb * 4) + 255) / 256 * 256;
    int* jsv = (int*)wsp;
    wsp += (((size_t)J * 4) + 255) / 256 * 256;
    uint4* wfrag = (uint4*)wsp;            // 20*64*16 B
    wsp += 20 * 64 * 16;
    float4* bfrag = (float4*)wsp;          // 3*64*16 B
    wsp += 3 * 64 * 16;
    unsigned* s16 = (unsigned*)wsp;        // [4][J][16 f16] = J*128 bytes

    k_prep<<<4 * nb + 1, TPB, 0, stream>>>(x, h_dag, h_glob, ptr, job_indices, num_exec_acts,
                                           J, nb, s16, bsum, jsv,
                                           W1, b1, W2, b2, W3, b3, W4, wfrag, bfrag);

    int numTiles = (T + 127) / 128;
    int grid = numTiles < 2048 ? numTiles : 2048;
    int chunk = (numTiles + grid - 1) / grid;
    grid = (numTiles + chunk - 1) / chunk;
    k_mlp_mfma<<<grid, TPB, 0, stream>>>(s16, W1, b2, jsv, bsum, wfrag, bfrag, b4,
                                         out, T, J, nb, numTiles, chunk);
}

// Round 14
// 152.169 us; speedup vs baseline: 1.0152x; 1.0152x over previous
//
#include <hip/hip_runtime.h>

#define TPB 256

using half8  = __attribute__((ext_vector_type(8))) _Float16;
using fp16x2 = __attribute__((ext_vector_type(2))) __fp16;
using hv2    = __attribute__((ext_vector_type(2))) _Float16;
using f32x4  = __attribute__((ext_vector_type(4))) float;

static __device__ __forceinline__ unsigned pkrtz(float a, float b) {
    fp16x2 h = __builtin_amdgcn_cvt_pkrtz(a, b);
    return __builtin_bit_cast(unsigned, h);
}
static __device__ __forceinline__ hv2 pk2(float a, float b) {
    fp16x2 h = __builtin_amdgcn_cvt_pkrtz(a, b);
    return __builtin_bit_cast(hv2, h);
}
template <int CTRL>
static __device__ __forceinline__ float dppmov(float x) {
    return __int_as_float(__builtin_amdgcn_mov_dpp(__float_as_int(x), CTRL, 0xF, 0xF, true));
}

// ---------- kernel 1: per-JOB shared L1 via 4-way split matvec (f16 s-table) + scan; last block: weight frags ----------
// W2 fragment uses column permutation sigma(nt,m) = 8*(m>>2) + (m&3) + 4*(nt&1) + 32*(nt>>1) so that the
// swapped-operand L2 MFMA (D = W2^T * h1^T) leaves lane (n,q) holding exactly h2[n][8q..8q+7 | 32+8q..+7],
// i.e. the ready-made L3 A-fragment — no LDS transpose needed in k_mlp.
__global__ __launch_bounds__(TPB) void k_prep(const float* __restrict__ x,
                                              const float* __restrict__ h_dag,
                                              const float* __restrict__ h_glob,
                                              const int* __restrict__ ptr,
                                              const int* __restrict__ job_indices,
                                              const int* __restrict__ num_exec_acts,
                                              int J, int nb,
                                              unsigned* __restrict__ s16,
                                              int* __restrict__ bsum, int* __restrict__ jsv,
                                              const float* __restrict__ W1,
                                              const float* __restrict__ b1,
                                              const float* __restrict__ W2,
                                              const float* __restrict__ b2,
                                              const float* __restrict__ W3,
                                              const float* __restrict__ b3,
                                              const float* __restrict__ W4,
                                              uint4* __restrict__ wfrag,
                                              float4* __restrict__ bfrag)
{
    if (blockIdx.x == (unsigned)(4 * nb)) {
        if (threadIdx.x < 64) {
            int lane = threadIdx.x;
            int n = lane & 15, q = lane >> 4;
#pragma unroll
            for (int nt = 0; nt < 4; nt++) {
                const int sig = 8 * (n >> 2) + (n & 3) + 4 * (nt & 1) + 32 * (nt >> 1);
#pragma unroll
                for (int s = 0; s < 2; s++) {
                    half8 w2f;
#pragma unroll
                    for (int jj = 0; jj < 8; jj++) {
                        int ks = s * 32 + q * 8 + jj;
                        w2f[jj] = (_Float16)W2[ks * 64 + sig];
                    }
                    wfrag[(8 + nt * 2 + s) * 64 + lane] = __builtin_bit_cast(uint4, w2f);
                }
            }
#pragma unroll
            for (int nt = 0; nt < 2; nt++) {
#pragma unroll
                for (int s = 0; s < 2; s++) {
                    half8 w3f;
#pragma unroll
                    for (int jj = 0; jj < 8; jj++) {
                        int ks = s * 32 + q * 8 + jj;
                        w3f[jj] = (_Float16)W3[ks * 32 + nt * 16 + n];
                    }
                    wfrag[(16 + nt * 2 + s) * 64 + lane] = __builtin_bit_cast(uint4, w3f);
                }
            }
            bfrag[2 * 64 + lane] = make_float4(b3[n], b3[16 + n], W4[n], W4[16 + n]);
        }
        return;
    }

    const int qtr = blockIdx.x / nb;        // 0..3
    const int cb  = blockIdx.x - qtr * nb;  // job block
    int j = cb * TPB + threadIdx.x;
    int v = 0;
    if (j < J) {
        int ji   = job_indices[j];
        if (qtr == 0) v = num_exec_acts[ji];
        int node = ptr[ji];
        float f[35];
        f[0] = x[node * 5 + 0];
        f[1] = x[node * 5 + 1];
        f[2] = x[node * 5 + 2];
        float4 hd[4], hg[4];
#pragma unroll
        for (int c4 = 0; c4 < 4; c4++) hd[c4] = *(const float4*)(h_dag + (size_t)ji * 16 + 4 * c4);
#pragma unroll
        for (int c4 = 0; c4 < 4; c4++) hg[c4] = *(const float4*)(h_glob + (size_t)j * 16 + 4 * c4);
#pragma unroll
        for (int c4 = 0; c4 < 4; c4++) {
            f[3 + 4 * c4 + 0]  = hd[c4].x; f[3 + 4 * c4 + 1]  = hd[c4].y;
            f[3 + 4 * c4 + 2]  = hd[c4].z; f[3 + 4 * c4 + 3]  = hd[c4].w;
            f[19 + 4 * c4 + 0] = hg[c4].x; f[19 + 4 * c4 + 1] = hg[c4].y;
            f[19 + 4 * c4 + 2] = hg[c4].z; f[19 + 4 * c4 + 3] = hg[c4].w;
        }
        float acc[16];
#pragma unroll
        for (int d4 = 0; d4 < 4; d4++) {
            float4 b = *(const float4*)(b1 + qtr * 16 + 4 * d4);
            acc[4 * d4 + 0] = b.x; acc[4 * d4 + 1] = b.y;
            acc[4 * d4 + 2] = b.z; acc[4 * d4 + 3] = b.w;
        }
#pragma unroll
        for (int c = 0; c < 35; c++) {
            float fc = f[c];
#pragma unroll
            for (int d4 = 0; d4 < 4; d4++) {
                float4 w = *(const float4*)(W1 + c * 64 + qtr * 16 + 4 * d4);
                acc[4 * d4 + 0] += fc * w.x; acc[4 * d4 + 1] += fc * w.y;
                acc[4 * d4 + 2] += fc * w.z; acc[4 * d4 + 3] += fc * w.w;
            }
        }
        unsigned* dst = s16 + ((size_t)qtr * J + j) * 8;
        ((uint4*)dst)[0] = make_uint4(pkrtz(acc[0], acc[1]),  pkrtz(acc[2], acc[3]),
                                      pkrtz(acc[4], acc[5]),  pkrtz(acc[6], acc[7]));
        ((uint4*)dst)[1] = make_uint4(pkrtz(acc[8], acc[9]),  pkrtz(acc[10], acc[11]),
                                      pkrtz(acc[12], acc[13]), pkrtz(acc[14], acc[15]));
    }
    if (qtr != 0) return;

    __shared__ int sc[TPB];
    sc[threadIdx.x] = v;
    __syncthreads();
    for (int d = 1; d < TPB; d <<= 1) {
        int add = (threadIdx.x >= d) ? sc[threadIdx.x - d] : 0;
        __syncthreads();
        sc[threadIdx.x] += add;
        __syncthreads();
    }
    if (j < J) jsv[j] = ((sc[threadIdx.x] - v) << 6) | v;
    if (threadIdx.x == TPB - 1) bsum[cb] = sc[TPB - 1];
}

// ---------- kernel 2: MLP from f16 s-table; register dataflow (swapped-L2); half-B gather prefetch ----------
__global__ __launch_bounds__(TPB) void k_mlp_mfma(const unsigned* __restrict__ s16,
                                                  const float* __restrict__ W1,
                                                  const float* __restrict__ b2,
                                                  const int* __restrict__ jsv,
                                                  const int* __restrict__ bsum,
                                                  const uint4* __restrict__ wfrag,
                                                  const float4* __restrict__ bfrag,
                                                  const float* __restrict__ b4,
                                                  float* __restrict__ out,
                                                  int T, int J, int nb, int numTiles, int chunk)
{
    __shared__ int boffs[TPB];                       // exclusive scan of bsum
    __shared__ int swin[4][64];                      // per-wave job-start window
    __shared__ int srow[4][64];                      // per-wave per-row (abs_job<<8|exec) for 64 rows
    const int tid  = threadIdx.x;
    const int lane = tid & 63;
    const int wv   = tid >> 6;
    const int n    = lane & 15;
    const int q    = lane >> 4;

    // ---- block-local exclusive scan of bsum (nb <= 256) ----
    {
        int v = (tid < nb) ? bsum[tid] : 0;
        boffs[tid] = v;
        __syncthreads();
        for (int d = 1; d < TPB; d <<= 1) {
            int add = (tid >= d) ? boffs[tid - d] : 0;
            __syncthreads();
            boffs[tid] += add;
            __syncthreads();
        }
        int ex = boffs[tid] - v;
        __syncthreads();
        boffs[tid] = ex;
        __syncthreads();
    }

    // ---- fragment loads: L2/L3 weights + biases ----
    half8 bw2[4][2], bw3[2][2];
#pragma unroll
    for (int nt = 0; nt < 4; nt++)
#pragma unroll
        for (int s = 0; s < 2; s++)
            bw2[nt][s] = __builtin_bit_cast(half8, wfrag[(8 + nt * 2 + s) * 64 + lane]);
#pragma unroll
    for (int nt = 0; nt < 2; nt++)
#pragma unroll
        for (int s = 0; s < 2; s++)
            bw3[nt][s] = __builtin_bit_cast(half8, wfrag[(16 + nt * 2 + s) * 64 + lane]);

    // swapped-L2 bias: acc2[nt][r] = b2[sigma(nt,4q+r)] = b2[8q + 4*(nt&1) + 32*(nt>>1) + r]
    float4 bb2q[4];
#pragma unroll
    for (int nt = 0; nt < 4; nt++)
        bb2q[nt] = *(const float4*)(b2 + 8 * q + 4 * (nt & 1) + 32 * (nt >> 1));

    float4 bf3 = bfrag[2 * 64 + lane];
    float bb3[2] = {bf3.x, bf3.y};
    const float w4a = bf3.z, w4b = bf3.w;
    const float b4v = b4[0];

    // ---- per-lane w36 slice as f16 pairs ----
    hv2 w36p[8];
    {
        const float* wp = W1 + 35 * 64 + q * 8;
#pragma unroll
        for (int k = 0; k < 4; k++) w36p[k]     = pk2(wp[2 * k],      wp[2 * k + 1]);
#pragma unroll
        for (int k = 0; k < 4; k++) w36p[4 + k] = pk2(wp[32 + 2 * k], wp[32 + 2 * k + 1]);
    }
    const hv2 z2 = {(_Float16)0.0f, (_Float16)0.0f};

    // ---- lane-constant s16 base pointers ----
    const uint4* sbLo = (const uint4*)s16 + ((size_t)(q >> 1) * J) * 2 + (q & 1);
    const uint4* sbHi = (const uint4*)s16 + ((size_t)(2 + (q >> 1)) * J) * 2 + (q & 1);

    // ---- per-block contiguous tile range; wave wv owns the wv-th quarter ----
    const int t0 = blockIdx.x * chunk;
    const int t1 = (t0 + chunk < numTiles) ? (t0 + chunk) : numTiles;
    const int R  = (t1 - t0) * 32;
    const int r0 = t0 * 128 + wv * R;
    int rend = r0 + R;
    if (rend > T) rend = T;

    if (r0 < rend) {
        int j_lo;
        {
            int lo = 0, hi = nb - 1;
            while (lo < hi) {
                int mid = (lo + hi + 1) >> 1;
                if (boffs[mid] <= r0) lo = mid; else hi = mid - 1;
            }
            j_lo = lo << 8;
        }
        int sreg    = 0;
        int win_top = 0x80000000;

        half8 a2[2][2];   // h1 A-frags (== B-frags of h1^T) for one 32-row half

        // pk-math: (lo,hi,e) -> a2[m]
        auto mk_a2 = [&](int m, uint4 lo, uint4 hi, float e) {
            hv2 epk = pk2(e, e);
            hv2 r0_ = __builtin_elementwise_max(__builtin_bit_cast(hv2, lo.x) + epk * w36p[0], z2);
            hv2 r1_ = __builtin_elementwise_max(__builtin_bit_cast(hv2, lo.y) + epk * w36p[1], z2);
            hv2 r2_ = __builtin_elementwise_max(__builtin_bit_cast(hv2, lo.z) + epk * w36p[2], z2);
            hv2 r3_ = __builtin_elementwise_max(__builtin_bit_cast(hv2, lo.w) + epk * w36p[3], z2);
            a2[m][0] = __builtin_bit_cast(half8, make_uint4(__builtin_bit_cast(unsigned, r0_),
                                                            __builtin_bit_cast(unsigned, r1_),
                                                            __builtin_bit_cast(unsigned, r2_),
                                                            __builtin_bit_cast(unsigned, r3_)));
            hv2 r4_ = __builtin_elementwise_max(__builtin_bit_cast(hv2, hi.x) + epk * w36p[4], z2);
            hv2 r5_ = __builtin_elementwise_max(__builtin_bit_cast(hv2, hi.y) + epk * w36p[5], z2);
            hv2 r6_ = __builtin_elementwise_max(__builtin_bit_cast(hv2, hi.z) + epk * w36p[6], z2);
            hv2 r7_ = __builtin_elementwise_max(__builtin_bit_cast(hv2, hi.w) + epk * w36p[7], z2);
            a2[m][1] = __builtin_bit_cast(half8, make_uint4(__builtin_bit_cast(unsigned, r4_),
                                                            __builtin_bit_cast(unsigned, r5_),
                                                            __builtin_bit_cast(unsigned, r6_),
                                                            __builtin_bit_cast(unsigned, r7_)));
        };

        // ---- full register pipeline for one 16-row m-tile: swapped L2 -> relu/pack -> L3 -> L4 reduce ----
        auto process_mt = [&](int mt, int rbb) {
            f32x4 acc2[4];
#pragma unroll
            for (int nt = 0; nt < 4; nt++) {
                f32x4 c; c[0] = bb2q[nt].x; c[1] = bb2q[nt].y; c[2] = bb2q[nt].z; c[3] = bb2q[nt].w;
                acc2[nt] = c;
            }
#pragma unroll
            for (int s = 0; s < 2; s++)
#pragma unroll
                for (int nt = 0; nt < 4; nt++)
                    acc2[nt] = __builtin_amdgcn_mfma_f32_16x16x32_f16(bw2[nt][s], a2[mt][s], acc2[nt], 0, 0, 0);

            half8 a3[2];
#pragma unroll
            for (int s = 0; s < 2; s++) {
                unsigned u0 = pkrtz(fmaxf(acc2[2 * s][0], 0.0f),     fmaxf(acc2[2 * s][1], 0.0f));
                unsigned u1 = pkrtz(fmaxf(acc2[2 * s][2], 0.0f),     fmaxf(acc2[2 * s][3], 0.0f));
                unsigned u2 = pkrtz(fmaxf(acc2[2 * s + 1][0], 0.0f), fmaxf(acc2[2 * s + 1][1], 0.0f));
                unsigned u3 = pkrtz(fmaxf(acc2[2 * s + 1][2], 0.0f), fmaxf(acc2[2 * s + 1][3], 0.0f));
                a3[s] = __builtin_bit_cast(half8, make_uint4(u0, u1, u2, u3));
            }

            f32x4 acc3[2];
#pragma unroll
            for (int nt2 = 0; nt2 < 2; nt2++) { f32x4 c; c[0]=c[1]=c[2]=c[3]=bb3[nt2]; acc3[nt2]=c; }
#pragma unroll
            for (int s = 0; s < 2; s++)
#pragma unroll
                for (int nt2 = 0; nt2 < 2; nt2++)
                    acc3[nt2] = __builtin_amdgcn_mfma_f32_16x16x32_f16(a3[s], bw3[nt2][s], acc3[nt2], 0, 0, 0);

            f32x4 red;
#pragma unroll
            for (int r = 0; r < 4; r++)
                red[r] = fmaxf(acc3[0][r], 0.0f) * w4a + fmaxf(acc3[1][r], 0.0f) * w4b;
#pragma unroll
            for (int r = 0; r < 4; r++) {
                red[r] += dppmov<0x121>(red[r]);   // row_ror:1
                red[r] += dppmov<0x122>(red[r]);   // row_ror:2
                red[r] += dppmov<0x124>(red[r]);   // row_ror:4
                red[r] += dppmov<0x128>(red[r]);   // row_ror:8
            }
            int t = rbb + 16 * mt + q * 4 + n;
            float val = (n == 0) ? red[0] : (n == 1) ? red[1] : (n == 2) ? red[2] : red[3];
            if (n < 4 && t < T) out[t] = val + b4v;
        };

        for (int rb = r0; rb < rend; rb += 64) {
            // ---- refill job-start window when it may not cover [rb, rb+64) ----
            if (win_top <= rb + 63) {
                for (;;) {
                    int jj = j_lo + lane;
                    sreg = (jj < J) ? (boffs[jj >> 8] + (jsv[jj] >> 6)) : 0x7fffffff;
                    unsigned long long m = __ballot(sreg <= rb);
                    int adv = 63 - __builtin_clzll(m);
                    j_lo += adv;
                    if (adv == 0) break;
                }
                swin[wv][lane] = sreg;
                win_top = __shfl(sreg, 63);
            }

            // ---- full-wave per-row search: lane resolves row rb+lane; store ABSOLUTE job ----
            {
                int rt = rb + lane;
                const int* sw = swin[wv];
                int lj = 0;
#pragma unroll
                for (int stp = 32; stp; stp >>= 1) {
                    int c2 = lj + stp;
                    if (c2 < 64 && sw[c2] <= rt) lj = c2;
                }
                int job = j_lo + lj;
                if (job > J - 1) job = J - 1;
                srow[wv][lane] = (job << 8) | (rt - sw[lj]);
            }
            // same-wave LDS: DS pipe is in-order, no barrier needed

            const bool hasB = (rb + 32 < rend);

            // ---- prefetch half-B s16 gathers; latency hides under half-A compute (T14 pattern) ----
            uint4 glB[2], ghB[2];
            float eB[2];
            if (hasB) {
#pragma unroll
                for (int m = 0; m < 2; m++) {
                    int u   = srow[wv][16 * (2 + m) + n];
                    int job = u >> 8;
                    eB[m]   = (float)(u & 255) * 0.02f;
                    glB[m]  = sbLo[(size_t)job * 2];
                    ghB[m]  = sbHi[(size_t)job * 2];
                }
            }

            // ---- half A: direct gather + build + process ----
#pragma unroll
            for (int m = 0; m < 2; m++) {
                int u   = srow[wv][16 * m + n];
                int job = u >> 8;
                float e = (float)(u & 255) * 0.02f;
                uint4 lo = sbLo[(size_t)job * 2];
                uint4 hi = sbHi[(size_t)job * 2];
                mk_a2(m, lo, hi, e);
            }
            process_mt(0, rb);
            process_mt(1, rb);

            // ---- half B: build from prefetched regs + process ----
            if (hasB) {
                mk_a2(0, glB[0], ghB[0], eB[0]);
                mk_a2(1, glB[1], ghB[1], eB[1]);
                process_mt(0, rb + 32);
                process_mt(1, rb + 32);
            }
        }
    }
}

extern "C" void kernel_launch(void* const* d_in, const int* in_sizes, int n_in,
                              void* d_out, int out_size, void* d_ws, size_t ws_size,
                              hipStream_t stream)
{
    const float* x             = (const float*)d_in[0];
    const float* h_dag         = (const float*)d_in[1];
    const float* h_glob        = (const float*)d_in[2];
    const int*   ptr           = (const int*)d_in[3];
    const int*   job_indices   = (const int*)d_in[4];
    const int*   num_exec_acts = (const int*)d_in[5];
    const float* W1 = (const float*)d_in[7];
    const float* b1 = (const float*)d_in[8];
    const float* W2 = (const float*)d_in[9];
    const float* b2 = (const float*)d_in[10];
    const float* W3 = (const float*)d_in[11];
    const float* b3 = (const float*)d_in[12];
    const float* W4 = (const float*)d_in[13];
    const float* b4 = (const float*)d_in[14];
    float* out = (float*)d_out;

    int J  = in_sizes[4];
    int T  = in_sizes[6];
    int nb = (J + TPB - 1) / TPB;

    // workspace layout
    char* wsp = (char*)d_ws;
    int* bsum = (int*)wsp;
    wsp += (((size_t)nb * 4) + 255) / 256 * 256;
    int* jsv = (int*)wsp;
    wsp += (((size_t)J * 4) + 255) / 256 * 256;
    uint4* wfrag = (uint4*)wsp;            // 20*64*16 B
    wsp += 20 * 64 * 16;
    float4* bfrag = (float4*)wsp;          // 3*64*16 B
    wsp += 3 * 64 * 16;
    unsigned* s16 = (unsigned*)wsp;        // [4][J][16 f16] = J*128 bytes

    k_prep<<<4 * nb + 1, TPB, 0, stream>>>(x, h_dag, h_glob, ptr, job_indices, num_exec_acts,
                                           J, nb, s16, bsum, jsv,
                                           W1, b1, W2, b2, W3, b3, W4, wfrag, bfrag);

    int numTiles = (T + 127) / 128;
    int grid = numTiles < 2048 ? numTiles : 2048;
    int chunk = (numTiles + grid - 1) / grid;
    grid = (numTiles + chunk - 1) / chunk;
    k_mlp_mfma<<<grid, TPB, 0, stream>>>(s16, W1, b2, jsv, bsum, wfrag, bfrag, b4,
                                         out, T, J, nb, numTiles, chunk);
}